// Round 2
// baseline (450.517 us; speedup 1.0000x reference)
//
#include <hip/hip_runtime.h>
#include <cmath>

#define BB 16
#define CC 64
#define PP 16384   // H*W = 128*128

typedef float f32x4 __attribute__((ext_vector_type(4)));

// ---------------------------------------------------------------------------
// Kernel 1: channel means. grid = B*4*C = 4096 blocks, one 64 KiB plane each.
// 16 fully-unrolled float4 loads per thread -> pure BW. Shuffle reduce.
// ---------------------------------------------------------------------------
__global__ __launch_bounds__(256) void k_means(const float* __restrict__ low,
                                               const float* __restrict__ high,
                                               const float* __restrict__ flow,
                                               const float* __restrict__ fb,
                                               float* __restrict__ cf) {
    int blk = blockIdx.x;                  // b*256 + t*64 + c
    int b = blk >> 8, t = (blk >> 6) & 3, c = blk & 63;
    const float* in = (t == 0) ? low : (t == 1) ? high : (t == 2) ? flow : fb;
    const float4* p = (const float4*)(in + ((size_t)(b * CC + c)) * PP);
    int tid = threadIdx.x;

    float s = 0.f;
    #pragma unroll
    for (int i = 0; i < 16; ++i) {
        float4 v = p[tid + i * 256];
        s += (v.x + v.y) + (v.z + v.w);
    }
    #pragma unroll
    for (int off = 32; off > 0; off >>= 1) s += __shfl_down(s, off, 64);

    __shared__ float r[4];
    if ((tid & 63) == 0) r[tid >> 6] = s;
    __syncthreads();
    if (tid == 0)
        cf[(b * 4 + t) * CC + c] = ((r[0] + r[1]) + (r[2] + r[3])) * (1.0f / PP);
}

// ---------------------------------------------------------------------------
// Kernel 2: adjacency + GCN + SE heads + effective mixing matrices.
// grid = B blocks, 256 threads. Amat[b][t][c][o], o contiguous.
// ---------------------------------------------------------------------------
__global__ __launch_bounds__(256) void k_small(const float* __restrict__ cf,
    const float* __restrict__ Wgcn, const float* __restrict__ bgcn,
    const float* __restrict__ W1, const float* __restrict__ b1,
    const float* __restrict__ W2, const float* __restrict__ b2,
    const float* __restrict__ W3, const float* __restrict__ b3,
    const float* __restrict__ W4, const float* __restrict__ b4,
    const float* __restrict__ Wgate,
    float* __restrict__ Amat) {
    int b = blockIdx.x;
    int tid = threadIdx.x;
    int lane = tid & 63;
    int wid = tid >> 6;                    // wave-uniform
    __shared__ float x[4][64];
    __shared__ float nrm[4];
    __shared__ float adj[16];
    __shared__ float y[4][64];
    __shared__ float fc[256];
    __shared__ float e[4][64];

    x[wid][lane] = cf[b * 256 + tid];
    __syncthreads();

    if (tid < 4) {
        float s = 0.f;
        for (int c = 0; c < 64; ++c) s += x[tid][c] * x[tid][c];
        nrm[tid] = sqrtf(s);
    }
    __syncthreads();

    if (tid < 16) {
        int i = tid >> 2, j = tid & 3;
        float s = 0.f;
        for (int c = 0; c < 64; ++c) s += x[i][c] * x[j][c];
        adj[tid] = s / (nrm[i] * nrm[j]);
    }
    __syncthreads();

    {   // y = adj @ x
        float s = 0.f;
        #pragma unroll
        for (int j = 0; j < 4; ++j) s += adj[wid * 4 + j] * x[j][lane];
        y[wid][lane] = s;
    }
    __syncthreads();

    {   // fc = relu(y @ Wgcn + bgcn)
        float s = bgcn[lane];
        for (int c = 0; c < 64; ++c) s += y[wid][c] * Wgcn[c * 64 + lane];
        fc[wid * 64 + lane] = fmaxf(s, 0.f);
    }
    __syncthreads();

    {   // e_k = sigmoid(fc @ Wk^T + bk); wave wid handles head wid.
        // Coalesced: lanes split the 256-dim; one output row per iteration.
        const float* Wk = (wid == 0) ? W1 : (wid == 1) ? W2 : (wid == 2) ? W3 : W4;
        const float* bk = (wid == 0) ? b1 : (wid == 1) ? b2 : (wid == 2) ? b3 : b4;
        float4 fv = *(const float4*)&fc[lane * 4];
        for (int c = 0; c < 64; ++c) {
            float4 w = *(const float4*)(Wk + c * 256 + lane * 4);
            float part = (w.x * fv.x + w.y * fv.y) + (w.z * fv.z + w.w * fv.w);
            #pragma unroll
            for (int off = 32; off > 0; off >>= 1)
                part += __shfl_down(part, off, 64);
            if (lane == 0) {
                float s = part + bk[c];
                e[wid][c] = 1.f / (1.f + expf(-s));
            }
        }
    }
    __syncthreads();

    // A[t][c][o] = Wg[o,t*64+c] + e[t][c]*(sum_q Wg[o,q*64+c] - Wg[o,t*64+c])
    // thread = (t=wid, o=lane); loop c in float4 chunks. Writes coalesced in o.
    {
        int t = wid, o = lane;
        const float* wrow = Wgate + o * 256;
        float* Ab = Amat + b * 16384 + t * 4096;
        #pragma unroll 4
        for (int c4 = 0; c4 < 64; c4 += 4) {
            float4 w0 = *(const float4*)(wrow + c4);
            float4 w1 = *(const float4*)(wrow + 64 + c4);
            float4 w2 = *(const float4*)(wrow + 128 + c4);
            float4 w3 = *(const float4*)(wrow + 192 + c4);
            float4 wt = (t == 0) ? w0 : (t == 1) ? w1 : (t == 2) ? w2 : w3;
            float4 sm = make_float4((w0.x + w1.x) + (w2.x + w3.x),
                                    (w0.y + w1.y) + (w2.y + w3.y),
                                    (w0.z + w1.z) + (w2.z + w3.z),
                                    (w0.w + w1.w) + (w2.w + w3.w));
            Ab[(c4 + 0) * 64 + o] = wt.x + e[t][c4 + 0] * (sm.x - wt.x);
            Ab[(c4 + 1) * 64 + o] = wt.y + e[t][c4 + 1] * (sm.y - wt.y);
            Ab[(c4 + 2) * 64 + o] = wt.z + e[t][c4 + 2] * (sm.z - wt.z);
            Ab[(c4 + 3) * 64 + o] = wt.w + e[t][c4 + 3] * (sm.w - wt.w);
        }
    }
}

// ---------------------------------------------------------------------------
// Kernel 3: out[b,o,p] = sum_t sum_c A[b][t][c][o] * x_t[b,c,p] + bgate[o]
// grid = B*64 blocks (256 pixels/tile), 256 threads.
// t-loop fused into c-loop: 4 independent load streams per iteration,
// unroll 2 -> 8 loads in flight over 2*256 FMA cycles.
// ---------------------------------------------------------------------------
__global__ __launch_bounds__(256, 4) void k_gemm(const float* __restrict__ low,
    const float* __restrict__ high, const float* __restrict__ flow,
    const float* __restrict__ fb, const float* __restrict__ Amat,
    const float* __restrict__ bgate, float* __restrict__ out) {
    int blk = blockIdx.x;
    int b = blk >> 6;
    int tile = blk & 63;
    int tid = threadIdx.x;
    int pt = tid & 63;
    int og = __builtin_amdgcn_readfirstlane(tid >> 6);   // wave-uniform
    int p0 = tile * 256 + pt * 4;

    size_t xoff = (size_t)b * (CC * PP) + p0;
    const float* pl = low  + xoff;
    const float* ph = high + xoff;
    const float* pf = flow + xoff;
    const float* pb = fb   + xoff;
    const float* Ab = Amat + b * 16384 + og * 16;   // + t*4096 + c*64 + j

    float acc[16][4];
    #pragma unroll
    for (int j = 0; j < 16; ++j)
        #pragma unroll
        for (int q = 0; q < 4; ++q) acc[j][q] = 0.f;

    #pragma unroll 2
    for (int c = 0; c < 64; ++c) {
        float4 x0 = *(const float4*)(pl + (size_t)c * PP);
        float4 x1 = *(const float4*)(ph + (size_t)c * PP);
        float4 x2 = *(const float4*)(pf + (size_t)c * PP);
        float4 x3 = *(const float4*)(pb + (size_t)c * PP);
        const float* A0 = Ab + c * 64;
        #pragma unroll
        for (int j = 0; j < 16; ++j) {
            float a0 = A0[j];
            float a1 = A0[4096 + j];
            float a2 = A0[8192 + j];
            float a3 = A0[12288 + j];
            acc[j][0] += a0 * x0.x + a1 * x1.x + a2 * x2.x + a3 * x3.x;
            acc[j][1] += a0 * x0.y + a1 * x1.y + a2 * x2.y + a3 * x3.y;
            acc[j][2] += a0 * x0.z + a1 * x1.z + a2 * x2.z + a3 * x3.z;
            acc[j][3] += a0 * x0.w + a1 * x1.w + a2 * x2.w + a3 * x3.w;
        }
    }

    #pragma unroll
    for (int j = 0; j < 16; ++j) {
        int o = og * 16 + j;
        float bg = bgate[o];
        f32x4 r;
        r.x = acc[j][0] + bg; r.y = acc[j][1] + bg;
        r.z = acc[j][2] + bg; r.w = acc[j][3] + bg;
        // nontemporal: don't evict the L3-resident inputs with the 64 MiB out
        __builtin_nontemporal_store(r, (f32x4*)(out + ((size_t)(b * CC + o)) * PP + p0));
    }
}

extern "C" void kernel_launch(void* const* d_in, const int* in_sizes, int n_in,
                              void* d_out, int out_size, void* d_ws, size_t ws_size,
                              hipStream_t stream) {
    const float* low  = (const float*)d_in[0];
    const float* high = (const float*)d_in[1];
    const float* flow = (const float*)d_in[2];
    const float* fb   = (const float*)d_in[3];
    const float* Wgcn = (const float*)d_in[4];
    const float* bgcn = (const float*)d_in[5];
    const float* W1   = (const float*)d_in[6];
    const float* b1   = (const float*)d_in[7];
    const float* W2   = (const float*)d_in[8];
    const float* b2   = (const float*)d_in[9];
    const float* W3   = (const float*)d_in[10];
    const float* b3   = (const float*)d_in[11];
    const float* W4   = (const float*)d_in[12];
    const float* b4   = (const float*)d_in[13];
    const float* Wgate = (const float*)d_in[14];
    const float* bgate = (const float*)d_in[15];
    float* out = (float*)d_out;

    float* cf   = (float*)d_ws;          // [16][4][64]
    float* Amat = (float*)d_ws + 4096;   // [16][4][64][64]

    k_means<<<BB * 4 * CC, 256, 0, stream>>>(low, high, flow, fb, cf);
    k_small<<<BB, 256, 0, stream>>>(cf, Wgcn, bgcn, W1, b1, W2, b2, W3, b3,
                                    W4, b4, Wgate, Amat);
    k_gemm<<<BB * CC, 256, 0, stream>>>(low, high, flow, fb, Amat, bgate, out);
}

// Round 3
// 426.099 us; speedup vs baseline: 1.0573x; 1.0573x over previous
//
#include <hip/hip_runtime.h>
#include <cmath>

#define BB 16
#define CC 64
#define PP 16384   // H*W = 128*128

typedef float f32x4 __attribute__((ext_vector_type(4)));
typedef float f32x2 __attribute__((ext_vector_type(2)));

// ---------------------------------------------------------------------------
// Kernel 1: channel means. grid = B*4*C = 4096 blocks, one 64 KiB plane each.
// ---------------------------------------------------------------------------
__global__ __launch_bounds__(256) void k_means(const float* __restrict__ low,
                                               const float* __restrict__ high,
                                               const float* __restrict__ flow,
                                               const float* __restrict__ fb,
                                               float* __restrict__ cf) {
    int blk = blockIdx.x;                  // b*256 + t*64 + c
    int b = blk >> 8, t = (blk >> 6) & 3, c = blk & 63;
    const float* in = (t == 0) ? low : (t == 1) ? high : (t == 2) ? flow : fb;
    const float4* p = (const float4*)(in + ((size_t)(b * CC + c)) * PP);
    int tid = threadIdx.x;

    float s = 0.f;
    #pragma unroll
    for (int i = 0; i < 16; ++i) {
        float4 v = p[tid + i * 256];
        s += (v.x + v.y) + (v.z + v.w);
    }
    #pragma unroll
    for (int off = 32; off > 0; off >>= 1) s += __shfl_down(s, off, 64);

    __shared__ float r[4];
    if ((tid & 63) == 0) r[tid >> 6] = s;
    __syncthreads();
    if (tid == 0)
        cf[(b * 4 + t) * CC + c] = ((r[0] + r[1]) + (r[2] + r[3])) * (1.0f / PP);
}

// ---------------------------------------------------------------------------
// Kernel 2: adjacency + GCN + SE heads + effective mixing matrices.
// grid = B blocks, 256 threads. Amat[b][t][c][o], o contiguous.
// ---------------------------------------------------------------------------
__global__ __launch_bounds__(256) void k_small(const float* __restrict__ cf,
    const float* __restrict__ Wgcn, const float* __restrict__ bgcn,
    const float* __restrict__ W1, const float* __restrict__ b1,
    const float* __restrict__ W2, const float* __restrict__ b2,
    const float* __restrict__ W3, const float* __restrict__ b3,
    const float* __restrict__ W4, const float* __restrict__ b4,
    const float* __restrict__ Wgate,
    float* __restrict__ Amat) {
    int b = blockIdx.x;
    int tid = threadIdx.x;
    int lane = tid & 63;
    int wid = tid >> 6;                    // wave-uniform
    __shared__ float x[4][64];
    __shared__ float nrm[4];
    __shared__ float adj[16];
    __shared__ float y[4][64];
    __shared__ float fc[256];
    __shared__ float e[4][64];

    x[wid][lane] = cf[b * 256 + tid];
    __syncthreads();

    if (tid < 4) {
        float s = 0.f;
        for (int c = 0; c < 64; ++c) s += x[tid][c] * x[tid][c];
        nrm[tid] = sqrtf(s);
    }
    __syncthreads();

    if (tid < 16) {
        int i = tid >> 2, j = tid & 3;
        float s = 0.f;
        for (int c = 0; c < 64; ++c) s += x[i][c] * x[j][c];
        adj[tid] = s / (nrm[i] * nrm[j]);
    }
    __syncthreads();

    {   // y = adj @ x
        float s = 0.f;
        #pragma unroll
        for (int j = 0; j < 4; ++j) s += adj[wid * 4 + j] * x[j][lane];
        y[wid][lane] = s;
    }
    __syncthreads();

    {   // fc = relu(y @ Wgcn + bgcn)
        float s = bgcn[lane];
        for (int c = 0; c < 64; ++c) s += y[wid][c] * Wgcn[c * 64 + lane];
        fc[wid * 64 + lane] = fmaxf(s, 0.f);
    }
    __syncthreads();

    {   // e_k = sigmoid(fc @ Wk^T + bk); wave wid handles head wid.
        const float* Wk = (wid == 0) ? W1 : (wid == 1) ? W2 : (wid == 2) ? W3 : W4;
        const float* bk = (wid == 0) ? b1 : (wid == 1) ? b2 : (wid == 2) ? b3 : b4;
        float4 fv = *(const float4*)&fc[lane * 4];
        for (int c = 0; c < 64; ++c) {
            float4 w = *(const float4*)(Wk + c * 256 + lane * 4);
            float part = (w.x * fv.x + w.y * fv.y) + (w.z * fv.z + w.w * fv.w);
            #pragma unroll
            for (int off = 32; off > 0; off >>= 1)
                part += __shfl_down(part, off, 64);
            if (lane == 0) {
                float s = part + bk[c];
                e[wid][c] = 1.f / (1.f + expf(-s));
            }
        }
    }
    __syncthreads();

    // A[t][c][o] = Wg[o,t*64+c] + e[t][c]*(sum_q Wg[o,q*64+c] - Wg[o,t*64+c])
    {
        int t = wid, o = lane;
        const float* wrow = Wgate + o * 256;
        float* Ab = Amat + b * 16384 + t * 4096;
        #pragma unroll 4
        for (int c4 = 0; c4 < 64; c4 += 4) {
            float4 w0 = *(const float4*)(wrow + c4);
            float4 w1 = *(const float4*)(wrow + 64 + c4);
            float4 w2 = *(const float4*)(wrow + 128 + c4);
            float4 w3 = *(const float4*)(wrow + 192 + c4);
            float4 wt = (t == 0) ? w0 : (t == 1) ? w1 : (t == 2) ? w2 : w3;
            float4 sm = make_float4((w0.x + w1.x) + (w2.x + w3.x),
                                    (w0.y + w1.y) + (w2.y + w3.y),
                                    (w0.z + w1.z) + (w2.z + w3.z),
                                    (w0.w + w1.w) + (w2.w + w3.w));
            Ab[(c4 + 0) * 64 + o] = wt.x + e[t][c4 + 0] * (sm.x - wt.x);
            Ab[(c4 + 1) * 64 + o] = wt.y + e[t][c4 + 1] * (sm.y - wt.y);
            Ab[(c4 + 2) * 64 + o] = wt.z + e[t][c4 + 2] * (sm.z - wt.z);
            Ab[(c4 + 3) * 64 + o] = wt.w + e[t][c4 + 3] * (sm.w - wt.w);
        }
    }
}

// ---------------------------------------------------------------------------
// Kernel 3: out[b,o,p] = sum_{t,c} A[b][t][c][o] * x_t[b,c,p] + bgate[o]
// grid = B*64 blocks (256 px/tile), 256 threads; wave owns 16 consecutive o.
// Inner product packed over o-pairs -> v_pk_fma_f32 (2 FMA/lane/cyc):
//   accp[j2][q] (float2 over o-pair) += A-pair (consecutive SGPRs) * splat(x_q)
// 128 pk_fma + 16 splats per c-iter vs 256 scalar fma before.
// ---------------------------------------------------------------------------
__global__ __launch_bounds__(256, 3) void k_gemm(const float* __restrict__ low,
    const float* __restrict__ high, const float* __restrict__ flow,
    const float* __restrict__ fb, const float* __restrict__ Amat,
    const float* __restrict__ bgate, float* __restrict__ out) {
    int blk = blockIdx.x;
    int b = blk >> 6;
    int tile = blk & 63;
    int tid = threadIdx.x;
    int pt = tid & 63;
    int og = __builtin_amdgcn_readfirstlane(tid >> 6);   // wave-uniform
    int p0 = tile * 256 + pt * 4;

    size_t xoff = (size_t)b * (CC * PP) + p0;
    const float* px[4] = {low + xoff, high + xoff, flow + xoff, fb + xoff};
    const float* Ab = Amat + b * 16384 + og * 16;   // + t*4096 + c*64 + j

    f32x2 acc[8][4];    // [o-pair][pixel]
    #pragma unroll
    for (int j2 = 0; j2 < 8; ++j2)
        #pragma unroll
        for (int q = 0; q < 4; ++q) acc[j2][q] = (f32x2)(0.f);

    #pragma unroll 2
    for (int c = 0; c < 64; ++c) {
        f32x4 xv[4];
        #pragma unroll
        for (int t = 0; t < 4; ++t)
            xv[t] = *(const f32x4*)(px[t] + (size_t)c * PP);
        #pragma unroll
        for (int t = 0; t < 4; ++t) {
            const f32x2* ap = (const f32x2*)(Ab + t * 4096 + c * 64);
            #pragma unroll
            for (int q = 0; q < 4; ++q) {
                f32x2 xb;
                xb.x = xv[t][q]; xb.y = xv[t][q];
                #pragma unroll
                for (int j2 = 0; j2 < 8; ++j2)
                    acc[j2][q] = __builtin_elementwise_fma(ap[j2], xb, acc[j2][q]);
            }
        }
    }

    #pragma unroll
    for (int j2 = 0; j2 < 8; ++j2) {
        #pragma unroll
        for (int par = 0; par < 2; ++par) {
            int o = og * 16 + j2 * 2 + par;
            float bg = bgate[o];
            f32x4 r;
            r.x = acc[j2][0][par] + bg;
            r.y = acc[j2][1][par] + bg;
            r.z = acc[j2][2][par] + bg;
            r.w = acc[j2][3][par] + bg;
            *(f32x4*)(out + ((size_t)(b * CC + o)) * PP + p0) = r;
        }
    }
}

extern "C" void kernel_launch(void* const* d_in, const int* in_sizes, int n_in,
                              void* d_out, int out_size, void* d_ws, size_t ws_size,
                              hipStream_t stream) {
    const float* low  = (const float*)d_in[0];
    const float* high = (const float*)d_in[1];
    const float* flow = (const float*)d_in[2];
    const float* fb   = (const float*)d_in[3];
    const float* Wgcn = (const float*)d_in[4];
    const float* bgcn = (const float*)d_in[5];
    const float* W1   = (const float*)d_in[6];
    const float* b1   = (const float*)d_in[7];
    const float* W2   = (const float*)d_in[8];
    const float* b2   = (const float*)d_in[9];
    const float* W3   = (const float*)d_in[10];
    const float* b3   = (const float*)d_in[11];
    const float* W4   = (const float*)d_in[12];
    const float* b4   = (const float*)d_in[13];
    const float* Wgate = (const float*)d_in[14];
    const float* bgate = (const float*)d_in[15];
    float* out = (float*)d_out;

    float* cf   = (float*)d_ws;          // [16][4][64]
    float* Amat = (float*)d_ws + 4096;   // [16][4][64][64]

    k_means<<<BB * 4 * CC, 256, 0, stream>>>(low, high, flow, fb, cf);
    k_small<<<BB, 256, 0, stream>>>(cf, Wgcn, bgcn, W1, b1, W2, b2, W3, b3,
                                    W4, b4, Wgate, Amat);
    k_gemm<<<BB * CC, 256, 0, stream>>>(low, high, flow, fb, Amat, bgate, out);
}